// Round 11
// baseline (116.293 us; speedup 1.0000x reference)
//
#include <hip/hip_runtime.h>
#include <math.h>

// ROUND 11 — MEASUREMENT ROUND. Kernel is byte-identical to R9 (best, 71.6us).
// kernel_launch fires it 4x back-to-back. Since dur_R9 = OH + K1, this round's
// dur = OH + K1 + 3*K_warm  =>  K_warm = (dur - 71.6)/3, independent of OH.
// Splits the ~24us kernel plateau into environment (dirty L3 after the 268MB
// poison fill) vs structure. Idempotent: kernel never reads d_out; same work
// every call (graph-capture safe).

#define NCAPS 1152
#define ILEN  8
#define OCAPS 64
#define OLEN  16
#define T     768
#define NWAVE 12
#define TPW   6          // n-tiles of 16 per wave (72 total)
#define NITER 3
#define OG    16
#define XT_PITCH 1156    // ushorts per xaugT row
#define E_PITCH  1160    // ushorts per eL row
#define SC_PITCH 20      // floats per Scmb[o][i] row

typedef __attribute__((ext_vector_type(8))) short short8;
typedef __attribute__((ext_vector_type(4))) float f32x4;

__device__ __forceinline__ unsigned f2bf_u(float f) {   // RNE float->bf16 bits
    unsigned u = __builtin_bit_cast(unsigned, f);
    return (u + 0x7FFFu + ((u >> 16) & 1u)) >> 16;
}
__device__ __forceinline__ unsigned pack2(float a, float b) {
    return f2bf_u(a) | (f2bf_u(b) << 16);
}
__device__ __forceinline__ float bf2f(unsigned h) {
    return __builtin_bit_cast(float, h << 16);
}
__device__ __forceinline__ short8 s8_from(unsigned a, unsigned b, unsigned c, unsigned d) {
    uint4 t = make_uint4(a, b, c, d);
    return __builtin_bit_cast(short8, t);
}

template<int CTRL>
__device__ __forceinline__ float dpp_add(float x) {
    int xi = __builtin_bit_cast(int, x);
    int r  = __builtin_amdgcn_update_dpp(0, xi, CTRL, 0xf, 0xf, true);
    return x + __builtin_bit_cast(float, r);
}
__device__ __forceinline__ float wave_sum63(float v) {
    v = dpp_add<0x111>(v);
    v = dpp_add<0x112>(v);
    v = dpp_add<0x114>(v);
    v = dpp_add<0x118>(v);
    v = dpp_add<0x142>(v);   // row_bcast:15
    v = dpp_add<0x143>(v);   // row_bcast:31
    return v;
}
__device__ __forceinline__ float allsum16(float v) {
    v = dpp_add<0xB1>(v);    // quad_perm xor1
    v = dpp_add<0x4E>(v);    // quad_perm xor2
    v = dpp_add<0x124>(v);   // row_ror:4
    v = dpp_add<0x128>(v);   // row_ror:8
    return v;
}

__global__ __launch_bounds__(T, 3) void caps_kernel(const float* __restrict__ x,
                                                    const float* __restrict__ w,
                                                    float* __restrict__ dout,
                                                    int probs_base) {
    const int tid  = threadIdx.x;
    const int lane = tid & 63;
    const int wid  = tid >> 6;
    const int l16  = lane & 15;
    const int quad = lane >> 4;
    const bool q0  = (quad == 0);
    const int b  = blockIdx.x >> 2;
    const int og = blockIdx.x & 3;

    __shared__ __align__(16) unsigned short pool[NCAPS * ILEN + 10 * XT_PITCH];
    __shared__ __align__(16) unsigned short Yl[OLEN][16];
    __shared__ __align__(16) float Wl[OG][OLEN][ILEN];
    __shared__ __align__(16) float Scmb[OLEN][OLEN][SC_PITCH];
    __shared__ float ZL[OG];
    unsigned short* xA    = pool;
    unsigned short* xaugT = pool + NCAPS * ILEN;

    if (tid < 512)
        ((float4*)&Wl[0][0][0])[tid] = ((const float4*)(w + (size_t)og * OG * OLEN * ILEN))[tid];
    if (tid < 128) ((unsigned*)&Yl[0][0])[tid] = 0;

    float a0 = 0.f, a1 = 0.f, a2 = 0.f, a3 = 0.f;
    float a4 = 0.f, a5 = 0.f, a6 = 0.f, a7 = 0.f;
    if (tid < NCAPS / 2) {
        const float4* xs = (const float4*)(x + (size_t)b * NCAPS * ILEN);
        float4 x0 = xs[4 * tid], x1 = xs[4 * tid + 1];
        float4 x2 = xs[4 * tid + 2], x3 = xs[4 * tid + 3];
        a0 = x0.x + x2.x; a1 = x0.y + x2.y; a2 = x0.z + x2.z; a3 = x0.w + x2.w;
        a4 = x1.x + x3.x; a5 = x1.y + x3.y; a6 = x1.z + x3.z; a7 = x1.w + x3.w;
        unsigned g0 = f2bf_u(x0.x), g1 = f2bf_u(x0.y), g2 = f2bf_u(x0.z), g3 = f2bf_u(x0.w);
        unsigned g4 = f2bf_u(x1.x), g5 = f2bf_u(x1.y), g6 = f2bf_u(x1.z), g7 = f2bf_u(x1.w);
        unsigned h0 = f2bf_u(x2.x), h1 = f2bf_u(x2.y), h2 = f2bf_u(x2.z), h3 = f2bf_u(x2.w);
        unsigned h4 = f2bf_u(x3.x), h5 = f2bf_u(x3.y), h6 = f2bf_u(x3.z), h7 = f2bf_u(x3.w);
        const int r0 = 2 * tid;
        *(uint4*)&xA[r0 * ILEN]       = make_uint4(g0 | (g1 << 16), g2 | (g3 << 16),
                                                   g4 | (g5 << 16), g6 | (g7 << 16));
        *(uint4*)&xA[(r0 + 1) * ILEN] = make_uint4(h0 | (h1 << 16), h2 | (h3 << 16),
                                                   h4 | (h5 << 16), h6 | (h7 << 16));
        *(unsigned*)&xaugT[0 * XT_PITCH + r0] = g0 | (h0 << 16);
        *(unsigned*)&xaugT[1 * XT_PITCH + r0] = g1 | (h1 << 16);
        *(unsigned*)&xaugT[2 * XT_PITCH + r0] = g2 | (h2 << 16);
        *(unsigned*)&xaugT[3 * XT_PITCH + r0] = g3 | (h3 << 16);
        *(unsigned*)&xaugT[4 * XT_PITCH + r0] = g4 | (h4 << 16);
        *(unsigned*)&xaugT[5 * XT_PITCH + r0] = g5 | (h5 << 16);
        *(unsigned*)&xaugT[6 * XT_PITCH + r0] = g6 | (h6 << 16);
        *(unsigned*)&xaugT[7 * XT_PITCH + r0] = g7 | (h7 << 16);
        *(unsigned*)&xaugT[8 * XT_PITCH + r0] = 0x3F803F80u;
    }
    for (int idx = tid; idx < XT_PITCH; idx += T) xaugT[9 * XT_PITCH + idx] = 0;

    a0 = wave_sum63(a0); a1 = wave_sum63(a1); a2 = wave_sum63(a2); a3 = wave_sum63(a3);
    a4 = wave_sum63(a4); a5 = wave_sum63(a5); a6 = wave_sum63(a6); a7 = wave_sum63(a7);
    if (lane == 63) {
        Scmb[0][0][wid] = a0; Scmb[0][1][wid] = a1;
        Scmb[0][2][wid] = a2; Scmb[0][3][wid] = a3;
        Scmb[0][4][wid] = a4; Scmb[0][5][wid] = a5;
        Scmb[0][6][wid] = a6; Scmb[0][7][wid] = a7;
    }
    __syncthreads();

    const int jr = (l16 < 9) ? l16 : 9;
    const unsigned short* xTw = xaugT + jr * XT_PITCH + wid * (TPW * 16) + 4 * quad;
    const unsigned short* xAw = xA + (wid * (TPW * 16) + l16) * ILEN;
    const short8 zs = {0, 0, 0, 0, 0, 0, 0, 0};
    const f32x4  zc = {0.f, 0.f, 0.f, 0.f};

    unsigned st0[TPW], st1[TPW];

    #pragma unroll
    for (int it = 0; it <= NITER; ++it) {
        if (it > 0) {
            short8 bL = q0 ? *(const short8*)&Yl[l16][0] : zs;
            f32x4 sacc = zc;
            #pragma unroll
            for (int tt = 0; tt < TPW; ++tt) {
                uint2 t2 = *(const uint2*)(xTw + tt * 16);
                short8 bs = s8_from(t2.x, t2.y, 0u, 0u);
                short8 aL = q0 ? *(const short8*)(xAw + tt * 128) : zs;
                f32x4 d = __builtin_amdgcn_mfma_f32_16x16x32_bf16(aL, bL, zc, 0, 0, 0);
                float e0 = __expf(d[0]), e1 = __expf(d[1]);
                float e2 = __expf(d[2]), e3 = __expf(d[3]);
                unsigned p0 = pack2(e0, e1), p1 = pack2(e2, e3);
                if (it == NITER) { st0[tt] = p0; st1[tt] = p1; }
                short8 as = s8_from(p0, p1, 0u, 0u);
                sacc = __builtin_amdgcn_mfma_f32_16x16x32_bf16(as, bs, sacc, 0, 0, 0);
            }
            #pragma unroll
            for (int r = 0; r < 4; ++r) Scmb[4 * quad + r][l16][wid] = sacc[r];
            __syncthreads();
        }

        if (tid < 256) {
            const int o = tid >> 4, l = tid & 15;
            const int oi = (it == 0) ? 0 : o;
            float sv[9];
            #pragma unroll
            for (int i = 0; i < 9; ++i) {
                float4 v0 = *(const float4*)&Scmb[oi][i][0];
                float4 v1 = *(const float4*)&Scmb[oi][i][4];
                float4 v2 = *(const float4*)&Scmb[oi][i][8];
                sv[i] = ((v0.x + v0.y) + (v0.z + v0.w))
                      + ((v1.x + v1.y) + (v1.z + v1.w))
                      + ((v2.x + v2.y) + (v2.z + v2.w));
            }
            if (it == 0) sv[8] = (float)NCAPS;
            const float zinv = 1.0f / sv[8];
            const float* wrow = &Wl[o][l][0];
            float outl = wrow[0] * sv[0];
            #pragma unroll
            for (int i = 1; i < ILEN; ++i) outl = fmaf(wrow[i], sv[i], outl);
            outl *= zinv;

            if (it < NITER) {
                float n2 = allsum16(outl * outl);
                const float inv = 1.0f / fmaxf(sqrtf(n2), 1e-12f);
                const float oh = outl * inv;
                #pragma unroll
                for (int i = 0; i < ILEN; ++i) {
                    float yi = allsum16(wrow[i] * oh);
                    if (l == i) Yl[o][i] = (unsigned short)f2bf_u(yi);
                }
            } else {
                dout[(((size_t)(b * OCAPS + og * OG + o)) << 4) + l] = outl;
                if (l == 0) ZL[o] = zinv;
            }
        }

        if (it == NITER) {
            unsigned short* eL = pool;
            const int n0 = wid * (TPW * 16) + 4 * quad;
            #pragma unroll
            for (int tt = 0; tt < TPW; ++tt) {
                *(unsigned*)&eL[l16 * E_PITCH + n0 + tt * 16]     = st0[tt];
                *(unsigned*)&eL[l16 * E_PITCH + n0 + tt * 16 + 2] = st1[tt];
            }
        }
        __syncthreads();
    }

    {
        const unsigned short* eL = pool;
        float* pbase = dout + (size_t)probs_base + (size_t)(b * OCAPS + og * OG) * NCAPS;
        #pragma unroll
        for (int j = 0; j < 6; ++j) {
            const int f = tid + j * T;
            const int o = f / (NCAPS / 4);
            const int c = f - o * (NCAPS / 4);
            const float zi = ZL[o];
            uint2 t = *(const uint2*)&eL[o * E_PITCH + 4 * c];
            float4 v;
            v.x = bf2f(t.x & 0xFFFFu) * zi;
            v.y = bf2f(t.x >> 16) * zi;
            v.z = bf2f(t.y & 0xFFFFu) * zi;
            v.w = bf2f(t.y >> 16) * zi;
            ((float4*)(pbase + (size_t)o * NCAPS))[c] = v;
        }
    }
}

extern "C" void kernel_launch(void* const* d_in, const int* in_sizes, int n_in,
                              void* d_out, int out_size, void* d_ws, size_t ws_size,
                              hipStream_t stream) {
    const float* x = (const float*)d_in[0];
    const float* w = (const float*)d_in[1];
    float* out = (float*)d_out;
    const int Bv = in_sizes[0] / (NCAPS * ILEN);        // 64
    const int nblocks = Bv * (OCAPS / OG);              // 256
    const int probs_base = Bv * OCAPS * OLEN;           // 65536
    // 4 identical launches: dur - 71.6 = 3 * K_warm (slope experiment).
    caps_kernel<<<dim3(nblocks), dim3(T), 0, stream>>>(x, w, out, probs_base);
    caps_kernel<<<dim3(nblocks), dim3(T), 0, stream>>>(x, w, out, probs_base);
    caps_kernel<<<dim3(nblocks), dim3(T), 0, stream>>>(x, w, out, probs_base);
    caps_kernel<<<dim3(nblocks), dim3(T), 0, stream>>>(x, w, out, probs_base);
}

// Round 13
// 73.298 us; speedup vs baseline: 1.5866x; 1.5866x over previous
//
#include <hip/hip_runtime.h>
#include <math.h>

// CapsuleLinear routing — round 13 = R9 (best, 71.6us) with NONTEMPORAL stores
// (R12 fix: __builtin_nontemporal_store needs ext_vector_type, not HIP float4).
// R11 slope experiment: K_warm=14.9us, K_cold~24us => ~9us is cold-cache
// environment (L3 100% dirty with 268MB 0xAA poison at kernel start; every
// d_out write-allocate forces a dirty victim eviction to HBM). nt stores
// bypass L2/L3 allocate: no RFO, no poison evictions on the write path.

#define NCAPS 1152
#define ILEN  8
#define OCAPS 64
#define OLEN  16
#define T     768
#define NWAVE 12
#define TPW   6          // n-tiles of 16 per wave (72 total)
#define NITER 3
#define OG    16
#define XT_PITCH 1156    // ushorts per xaugT row
#define E_PITCH  1160    // ushorts per eL row
#define SC_PITCH 20      // floats per Scmb[o][i] row

typedef __attribute__((ext_vector_type(8))) short short8;
typedef __attribute__((ext_vector_type(4))) float f32x4;

__device__ __forceinline__ unsigned f2bf_u(float f) {   // RNE float->bf16 bits
    unsigned u = __builtin_bit_cast(unsigned, f);
    return (u + 0x7FFFu + ((u >> 16) & 1u)) >> 16;
}
__device__ __forceinline__ unsigned pack2(float a, float b) {
    return f2bf_u(a) | (f2bf_u(b) << 16);
}
__device__ __forceinline__ float bf2f(unsigned h) {
    return __builtin_bit_cast(float, h << 16);
}
__device__ __forceinline__ short8 s8_from(unsigned a, unsigned b, unsigned c, unsigned d) {
    uint4 t = make_uint4(a, b, c, d);
    return __builtin_bit_cast(short8, t);
}

template<int CTRL>
__device__ __forceinline__ float dpp_add(float x) {
    int xi = __builtin_bit_cast(int, x);
    int r  = __builtin_amdgcn_update_dpp(0, xi, CTRL, 0xf, 0xf, true);
    return x + __builtin_bit_cast(float, r);
}
__device__ __forceinline__ float wave_sum63(float v) {
    v = dpp_add<0x111>(v);
    v = dpp_add<0x112>(v);
    v = dpp_add<0x114>(v);
    v = dpp_add<0x118>(v);
    v = dpp_add<0x142>(v);   // row_bcast:15
    v = dpp_add<0x143>(v);   // row_bcast:31
    return v;
}
__device__ __forceinline__ float allsum16(float v) {
    v = dpp_add<0xB1>(v);    // quad_perm xor1
    v = dpp_add<0x4E>(v);    // quad_perm xor2
    v = dpp_add<0x124>(v);   // row_ror:4
    v = dpp_add<0x128>(v);   // row_ror:8
    return v;
}

__global__ __launch_bounds__(T, 3) void caps_kernel(const float* __restrict__ x,
                                                    const float* __restrict__ w,
                                                    float* __restrict__ dout,
                                                    int probs_base) {
    const int tid  = threadIdx.x;
    const int lane = tid & 63;
    const int wid  = tid >> 6;
    const int l16  = lane & 15;
    const int quad = lane >> 4;
    const bool q0  = (quad == 0);
    const int b  = blockIdx.x >> 2;
    const int og = blockIdx.x & 3;

    __shared__ __align__(16) unsigned short pool[NCAPS * ILEN + 10 * XT_PITCH];
    __shared__ __align__(16) unsigned short Yl[OLEN][16];
    __shared__ __align__(16) float Wl[OG][OLEN][ILEN];
    __shared__ __align__(16) float Scmb[OLEN][OLEN][SC_PITCH];
    __shared__ float ZL[OG];
    unsigned short* xA    = pool;
    unsigned short* xaugT = pool + NCAPS * ILEN;

    if (tid < 512)
        ((float4*)&Wl[0][0][0])[tid] = ((const float4*)(w + (size_t)og * OG * OLEN * ILEN))[tid];
    if (tid < 128) ((unsigned*)&Yl[0][0])[tid] = 0;

    float a0 = 0.f, a1 = 0.f, a2 = 0.f, a3 = 0.f;
    float a4 = 0.f, a5 = 0.f, a6 = 0.f, a7 = 0.f;
    if (tid < NCAPS / 2) {
        const float4* xs = (const float4*)(x + (size_t)b * NCAPS * ILEN);
        float4 x0 = xs[4 * tid], x1 = xs[4 * tid + 1];
        float4 x2 = xs[4 * tid + 2], x3 = xs[4 * tid + 3];
        a0 = x0.x + x2.x; a1 = x0.y + x2.y; a2 = x0.z + x2.z; a3 = x0.w + x2.w;
        a4 = x1.x + x3.x; a5 = x1.y + x3.y; a6 = x1.z + x3.z; a7 = x1.w + x3.w;
        unsigned g0 = f2bf_u(x0.x), g1 = f2bf_u(x0.y), g2 = f2bf_u(x0.z), g3 = f2bf_u(x0.w);
        unsigned g4 = f2bf_u(x1.x), g5 = f2bf_u(x1.y), g6 = f2bf_u(x1.z), g7 = f2bf_u(x1.w);
        unsigned h0 = f2bf_u(x2.x), h1 = f2bf_u(x2.y), h2 = f2bf_u(x2.z), h3 = f2bf_u(x2.w);
        unsigned h4 = f2bf_u(x3.x), h5 = f2bf_u(x3.y), h6 = f2bf_u(x3.z), h7 = f2bf_u(x3.w);
        const int r0 = 2 * tid;
        *(uint4*)&xA[r0 * ILEN]       = make_uint4(g0 | (g1 << 16), g2 | (g3 << 16),
                                                   g4 | (g5 << 16), g6 | (g7 << 16));
        *(uint4*)&xA[(r0 + 1) * ILEN] = make_uint4(h0 | (h1 << 16), h2 | (h3 << 16),
                                                   h4 | (h5 << 16), h6 | (h7 << 16));
        *(unsigned*)&xaugT[0 * XT_PITCH + r0] = g0 | (h0 << 16);
        *(unsigned*)&xaugT[1 * XT_PITCH + r0] = g1 | (h1 << 16);
        *(unsigned*)&xaugT[2 * XT_PITCH + r0] = g2 | (h2 << 16);
        *(unsigned*)&xaugT[3 * XT_PITCH + r0] = g3 | (h3 << 16);
        *(unsigned*)&xaugT[4 * XT_PITCH + r0] = g4 | (h4 << 16);
        *(unsigned*)&xaugT[5 * XT_PITCH + r0] = g5 | (h5 << 16);
        *(unsigned*)&xaugT[6 * XT_PITCH + r0] = g6 | (h6 << 16);
        *(unsigned*)&xaugT[7 * XT_PITCH + r0] = g7 | (h7 << 16);
        *(unsigned*)&xaugT[8 * XT_PITCH + r0] = 0x3F803F80u;
    }
    for (int idx = tid; idx < XT_PITCH; idx += T) xaugT[9 * XT_PITCH + idx] = 0;

    a0 = wave_sum63(a0); a1 = wave_sum63(a1); a2 = wave_sum63(a2); a3 = wave_sum63(a3);
    a4 = wave_sum63(a4); a5 = wave_sum63(a5); a6 = wave_sum63(a6); a7 = wave_sum63(a7);
    if (lane == 63) {
        Scmb[0][0][wid] = a0; Scmb[0][1][wid] = a1;
        Scmb[0][2][wid] = a2; Scmb[0][3][wid] = a3;
        Scmb[0][4][wid] = a4; Scmb[0][5][wid] = a5;
        Scmb[0][6][wid] = a6; Scmb[0][7][wid] = a7;
    }
    __syncthreads();

    const int jr = (l16 < 9) ? l16 : 9;
    const unsigned short* xTw = xaugT + jr * XT_PITCH + wid * (TPW * 16) + 4 * quad;
    const unsigned short* xAw = xA + (wid * (TPW * 16) + l16) * ILEN;
    const short8 zs = {0, 0, 0, 0, 0, 0, 0, 0};
    const f32x4  zc = {0.f, 0.f, 0.f, 0.f};

    unsigned st0[TPW], st1[TPW];

    #pragma unroll
    for (int it = 0; it <= NITER; ++it) {
        if (it > 0) {
            short8 bL = q0 ? *(const short8*)&Yl[l16][0] : zs;
            f32x4 sacc = zc;
            #pragma unroll
            for (int tt = 0; tt < TPW; ++tt) {
                uint2 t2 = *(const uint2*)(xTw + tt * 16);
                short8 bs = s8_from(t2.x, t2.y, 0u, 0u);
                short8 aL = q0 ? *(const short8*)(xAw + tt * 128) : zs;
                f32x4 d = __builtin_amdgcn_mfma_f32_16x16x32_bf16(aL, bL, zc, 0, 0, 0);
                float e0 = __expf(d[0]), e1 = __expf(d[1]);
                float e2 = __expf(d[2]), e3 = __expf(d[3]);
                unsigned p0 = pack2(e0, e1), p1 = pack2(e2, e3);
                if (it == NITER) { st0[tt] = p0; st1[tt] = p1; }
                short8 as = s8_from(p0, p1, 0u, 0u);
                sacc = __builtin_amdgcn_mfma_f32_16x16x32_bf16(as, bs, sacc, 0, 0, 0);
            }
            #pragma unroll
            for (int r = 0; r < 4; ++r) Scmb[4 * quad + r][l16][wid] = sacc[r];
            __syncthreads();
        }

        if (tid < 256) {
            const int o = tid >> 4, l = tid & 15;
            const int oi = (it == 0) ? 0 : o;
            float sv[9];
            #pragma unroll
            for (int i = 0; i < 9; ++i) {
                float4 v0 = *(const float4*)&Scmb[oi][i][0];
                float4 v1 = *(const float4*)&Scmb[oi][i][4];
                float4 v2 = *(const float4*)&Scmb[oi][i][8];
                sv[i] = ((v0.x + v0.y) + (v0.z + v0.w))
                      + ((v1.x + v1.y) + (v1.z + v1.w))
                      + ((v2.x + v2.y) + (v2.z + v2.w));
            }
            if (it == 0) sv[8] = (float)NCAPS;
            const float zinv = 1.0f / sv[8];
            const float* wrow = &Wl[o][l][0];
            float outl = wrow[0] * sv[0];
            #pragma unroll
            for (int i = 1; i < ILEN; ++i) outl = fmaf(wrow[i], sv[i], outl);
            outl *= zinv;

            if (it < NITER) {
                float n2 = allsum16(outl * outl);
                const float inv = 1.0f / fmaxf(sqrtf(n2), 1e-12f);
                const float oh = outl * inv;
                #pragma unroll
                for (int i = 0; i < ILEN; ++i) {
                    float yi = allsum16(wrow[i] * oh);
                    if (l == i) Yl[o][i] = (unsigned short)f2bf_u(yi);
                }
            } else {
                __builtin_nontemporal_store(
                    outl, &dout[(((size_t)(b * OCAPS + og * OG + o)) << 4) + l]);
                if (l == 0) ZL[o] = zinv;
            }
        }

        if (it == NITER) {
            unsigned short* eL = pool;
            const int n0 = wid * (TPW * 16) + 4 * quad;
            #pragma unroll
            for (int tt = 0; tt < TPW; ++tt) {
                *(unsigned*)&eL[l16 * E_PITCH + n0 + tt * 16]     = st0[tt];
                *(unsigned*)&eL[l16 * E_PITCH + n0 + tt * 16 + 2] = st1[tt];
            }
        }
        __syncthreads();
    }

    {
        const unsigned short* eL = pool;
        float* pbase = dout + (size_t)probs_base + (size_t)(b * OCAPS + og * OG) * NCAPS;
        #pragma unroll
        for (int j = 0; j < 6; ++j) {
            const int f = tid + j * T;
            const int o = f / (NCAPS / 4);
            const int c = f - o * (NCAPS / 4);
            const float zi = ZL[o];
            uint2 t = *(const uint2*)&eL[o * E_PITCH + 4 * c];
            f32x4 v;
            v[0] = bf2f(t.x & 0xFFFFu) * zi;
            v[1] = bf2f(t.x >> 16) * zi;
            v[2] = bf2f(t.y & 0xFFFFu) * zi;
            v[3] = bf2f(t.y >> 16) * zi;
            __builtin_nontemporal_store(v, (f32x4*)(pbase + (size_t)o * NCAPS) + c);
        }
    }
}

extern "C" void kernel_launch(void* const* d_in, const int* in_sizes, int n_in,
                              void* d_out, int out_size, void* d_ws, size_t ws_size,
                              hipStream_t stream) {
    const float* x = (const float*)d_in[0];
    const float* w = (const float*)d_in[1];
    float* out = (float*)d_out;
    const int Bv = in_sizes[0] / (NCAPS * ILEN);        // 64
    const int nblocks = Bv * (OCAPS / OG);              // 256
    const int probs_base = Bv * OCAPS * OLEN;           // 65536
    caps_kernel<<<dim3(nblocks), dim3(T), 0, stream>>>(x, w, out, probs_base);
}

// Round 14
// 72.068 us; speedup vs baseline: 1.6137x; 1.0171x over previous
//
#include <hip/hip_runtime.h>
#include <math.h>

// CapsuleLinear routing — FINAL: byte-identical revert to R9 (best, 71.6us).
// 13-round session summary:
//   dur = ~47.6us harness floor (287MB poison fills) + kernel.
//   Kernel: 24us cold / ~13us warm (R11 4x-launch slope measurement),
//   invariant across 8 structures (shuffle/DPP/MFMA/zero-LDS/NT-stores).
//   HBM floor for the kernel is ~3.5us; the residual is cold-start/latency
//   that no source-level lever moved. This kernel is the measured optimum.
// Structure: logits = Xb @ Y and S_aug = P^T @ [Xb|1] via
// mfma_f32_16x16x32_bf16 (A[m=lane&15][k=quad*8+j], C/D[col=lane&15][row=quad*4+reg]);
// grid 256 = 64b x 4og, T=768 (12 waves), it0 folded into prologue,
// DPP reductions, LDS-pool reuse for coalesced probs stores.

#define NCAPS 1152
#define ILEN  8
#define OCAPS 64
#define OLEN  16
#define T     768
#define NWAVE 12
#define TPW   6          // n-tiles of 16 per wave (72 total)
#define NITER 3
#define OG    16
#define XT_PITCH 1156    // ushorts per xaugT row
#define E_PITCH  1160    // ushorts per eL row
#define SC_PITCH 20      // floats per Scmb[o][i] row

typedef __attribute__((ext_vector_type(8))) short short8;
typedef __attribute__((ext_vector_type(4))) float f32x4;

__device__ __forceinline__ unsigned f2bf_u(float f) {   // RNE float->bf16 bits
    unsigned u = __builtin_bit_cast(unsigned, f);
    return (u + 0x7FFFu + ((u >> 16) & 1u)) >> 16;
}
__device__ __forceinline__ unsigned pack2(float a, float b) {
    return f2bf_u(a) | (f2bf_u(b) << 16);
}
__device__ __forceinline__ float bf2f(unsigned h) {
    return __builtin_bit_cast(float, h << 16);
}
__device__ __forceinline__ short8 s8_from(unsigned a, unsigned b, unsigned c, unsigned d) {
    uint4 t = make_uint4(a, b, c, d);
    return __builtin_bit_cast(short8, t);
}

template<int CTRL>
__device__ __forceinline__ float dpp_add(float x) {
    int xi = __builtin_bit_cast(int, x);
    int r  = __builtin_amdgcn_update_dpp(0, xi, CTRL, 0xf, 0xf, true);
    return x + __builtin_bit_cast(float, r);
}
__device__ __forceinline__ float wave_sum63(float v) {
    v = dpp_add<0x111>(v);   // row_shr:1
    v = dpp_add<0x112>(v);   // row_shr:2
    v = dpp_add<0x114>(v);   // row_shr:4
    v = dpp_add<0x118>(v);   // row_shr:8
    v = dpp_add<0x142>(v);   // row_bcast:15
    v = dpp_add<0x143>(v);   // row_bcast:31
    return v;
}
__device__ __forceinline__ float allsum16(float v) {
    v = dpp_add<0xB1>(v);    // quad_perm xor1
    v = dpp_add<0x4E>(v);    // quad_perm xor2
    v = dpp_add<0x124>(v);   // row_ror:4
    v = dpp_add<0x128>(v);   // row_ror:8
    return v;
}

__global__ __launch_bounds__(T, 3) void caps_kernel(const float* __restrict__ x,
                                                    const float* __restrict__ w,
                                                    float* __restrict__ dout,
                                                    int probs_base) {
    const int tid  = threadIdx.x;
    const int lane = tid & 63;
    const int wid  = tid >> 6;
    const int l16  = lane & 15;
    const int quad = lane >> 4;
    const bool q0  = (quad == 0);
    const int b  = blockIdx.x >> 2;
    const int og = blockIdx.x & 3;

    __shared__ __align__(16) unsigned short pool[NCAPS * ILEN + 10 * XT_PITCH];
    __shared__ __align__(16) unsigned short Yl[OLEN][16];
    __shared__ __align__(16) float Wl[OG][OLEN][ILEN];
    __shared__ __align__(16) float Scmb[OLEN][OLEN][SC_PITCH];
    __shared__ float ZL[OG];
    unsigned short* xA    = pool;
    unsigned short* xaugT = pool + NCAPS * ILEN;

    if (tid < 512)
        ((float4*)&Wl[0][0][0])[tid] = ((const float4*)(w + (size_t)og * OG * OLEN * ILEN))[tid];
    if (tid < 128) ((unsigned*)&Yl[0][0])[tid] = 0;

    float a0 = 0.f, a1 = 0.f, a2 = 0.f, a3 = 0.f;
    float a4 = 0.f, a5 = 0.f, a6 = 0.f, a7 = 0.f;
    if (tid < NCAPS / 2) {
        const float4* xs = (const float4*)(x + (size_t)b * NCAPS * ILEN);
        float4 x0 = xs[4 * tid], x1 = xs[4 * tid + 1];
        float4 x2 = xs[4 * tid + 2], x3 = xs[4 * tid + 3];
        a0 = x0.x + x2.x; a1 = x0.y + x2.y; a2 = x0.z + x2.z; a3 = x0.w + x2.w;
        a4 = x1.x + x3.x; a5 = x1.y + x3.y; a6 = x1.z + x3.z; a7 = x1.w + x3.w;
        unsigned g0 = f2bf_u(x0.x), g1 = f2bf_u(x0.y), g2 = f2bf_u(x0.z), g3 = f2bf_u(x0.w);
        unsigned g4 = f2bf_u(x1.x), g5 = f2bf_u(x1.y), g6 = f2bf_u(x1.z), g7 = f2bf_u(x1.w);
        unsigned h0 = f2bf_u(x2.x), h1 = f2bf_u(x2.y), h2 = f2bf_u(x2.z), h3 = f2bf_u(x2.w);
        unsigned h4 = f2bf_u(x3.x), h5 = f2bf_u(x3.y), h6 = f2bf_u(x3.z), h7 = f2bf_u(x3.w);
        const int r0 = 2 * tid;
        *(uint4*)&xA[r0 * ILEN]       = make_uint4(g0 | (g1 << 16), g2 | (g3 << 16),
                                                   g4 | (g5 << 16), g6 | (g7 << 16));
        *(uint4*)&xA[(r0 + 1) * ILEN] = make_uint4(h0 | (h1 << 16), h2 | (h3 << 16),
                                                   h4 | (h5 << 16), h6 | (h7 << 16));
        *(unsigned*)&xaugT[0 * XT_PITCH + r0] = g0 | (h0 << 16);
        *(unsigned*)&xaugT[1 * XT_PITCH + r0] = g1 | (h1 << 16);
        *(unsigned*)&xaugT[2 * XT_PITCH + r0] = g2 | (h2 << 16);
        *(unsigned*)&xaugT[3 * XT_PITCH + r0] = g3 | (h3 << 16);
        *(unsigned*)&xaugT[4 * XT_PITCH + r0] = g4 | (h4 << 16);
        *(unsigned*)&xaugT[5 * XT_PITCH + r0] = g5 | (h5 << 16);
        *(unsigned*)&xaugT[6 * XT_PITCH + r0] = g6 | (h6 << 16);
        *(unsigned*)&xaugT[7 * XT_PITCH + r0] = g7 | (h7 << 16);
        *(unsigned*)&xaugT[8 * XT_PITCH + r0] = 0x3F803F80u;
    }
    for (int idx = tid; idx < XT_PITCH; idx += T) xaugT[9 * XT_PITCH + idx] = 0;

    a0 = wave_sum63(a0); a1 = wave_sum63(a1); a2 = wave_sum63(a2); a3 = wave_sum63(a3);
    a4 = wave_sum63(a4); a5 = wave_sum63(a5); a6 = wave_sum63(a6); a7 = wave_sum63(a7);
    if (lane == 63) {
        Scmb[0][0][wid] = a0; Scmb[0][1][wid] = a1;
        Scmb[0][2][wid] = a2; Scmb[0][3][wid] = a3;
        Scmb[0][4][wid] = a4; Scmb[0][5][wid] = a5;
        Scmb[0][6][wid] = a6; Scmb[0][7][wid] = a7;
    }
    __syncthreads();

    const int jr = (l16 < 9) ? l16 : 9;
    const unsigned short* xTw = xaugT + jr * XT_PITCH + wid * (TPW * 16) + 4 * quad;
    const unsigned short* xAw = xA + (wid * (TPW * 16) + l16) * ILEN;
    const short8 zs = {0, 0, 0, 0, 0, 0, 0, 0};
    const f32x4  zc = {0.f, 0.f, 0.f, 0.f};

    unsigned st0[TPW], st1[TPW];

    #pragma unroll
    for (int it = 0; it <= NITER; ++it) {
        if (it > 0) {
            short8 bL = q0 ? *(const short8*)&Yl[l16][0] : zs;
            f32x4 sacc = zc;
            #pragma unroll
            for (int tt = 0; tt < TPW; ++tt) {
                uint2 t2 = *(const uint2*)(xTw + tt * 16);
                short8 bs = s8_from(t2.x, t2.y, 0u, 0u);
                short8 aL = q0 ? *(const short8*)(xAw + tt * 128) : zs;
                f32x4 d = __builtin_amdgcn_mfma_f32_16x16x32_bf16(aL, bL, zc, 0, 0, 0);
                float e0 = __expf(d[0]), e1 = __expf(d[1]);
                float e2 = __expf(d[2]), e3 = __expf(d[3]);
                unsigned p0 = pack2(e0, e1), p1 = pack2(e2, e3);
                if (it == NITER) { st0[tt] = p0; st1[tt] = p1; }
                short8 as = s8_from(p0, p1, 0u, 0u);
                sacc = __builtin_amdgcn_mfma_f32_16x16x32_bf16(as, bs, sacc, 0, 0, 0);
            }
            #pragma unroll
            for (int r = 0; r < 4; ++r) Scmb[4 * quad + r][l16][wid] = sacc[r];
            __syncthreads();
        }

        if (tid < 256) {
            const int o = tid >> 4, l = tid & 15;
            const int oi = (it == 0) ? 0 : o;
            float sv[9];
            #pragma unroll
            for (int i = 0; i < 9; ++i) {
                float4 v0 = *(const float4*)&Scmb[oi][i][0];
                float4 v1 = *(const float4*)&Scmb[oi][i][4];
                float4 v2 = *(const float4*)&Scmb[oi][i][8];
                sv[i] = ((v0.x + v0.y) + (v0.z + v0.w))
                      + ((v1.x + v1.y) + (v1.z + v1.w))
                      + ((v2.x + v2.y) + (v2.z + v2.w));
            }
            if (it == 0) sv[8] = (float)NCAPS;
            const float zinv = 1.0f / sv[8];
            const float* wrow = &Wl[o][l][0];
            float outl = wrow[0] * sv[0];
            #pragma unroll
            for (int i = 1; i < ILEN; ++i) outl = fmaf(wrow[i], sv[i], outl);
            outl *= zinv;

            if (it < NITER) {
                float n2 = allsum16(outl * outl);
                const float inv = 1.0f / fmaxf(sqrtf(n2), 1e-12f);
                const float oh = outl * inv;
                #pragma unroll
                for (int i = 0; i < ILEN; ++i) {
                    float yi = allsum16(wrow[i] * oh);
                    if (l == i) Yl[o][i] = (unsigned short)f2bf_u(yi);
                }
            } else {
                dout[(((size_t)(b * OCAPS + og * OG + o)) << 4) + l] = outl;
                if (l == 0) ZL[o] = zinv;
            }
        }

        if (it == NITER) {
            unsigned short* eL = pool;
            const int n0 = wid * (TPW * 16) + 4 * quad;
            #pragma unroll
            for (int tt = 0; tt < TPW; ++tt) {
                *(unsigned*)&eL[l16 * E_PITCH + n0 + tt * 16]     = st0[tt];
                *(unsigned*)&eL[l16 * E_PITCH + n0 + tt * 16 + 2] = st1[tt];
            }
        }
        __syncthreads();
    }

    {
        const unsigned short* eL = pool;
        float* pbase = dout + (size_t)probs_base + (size_t)(b * OCAPS + og * OG) * NCAPS;
        #pragma unroll
        for (int j = 0; j < 6; ++j) {
            const int f = tid + j * T;
            const int o = f / (NCAPS / 4);
            const int c = f - o * (NCAPS / 4);
            const float zi = ZL[o];
            uint2 t = *(const uint2*)&eL[o * E_PITCH + 4 * c];
            float4 v;
            v.x = bf2f(t.x & 0xFFFFu) * zi;
            v.y = bf2f(t.x >> 16) * zi;
            v.z = bf2f(t.y & 0xFFFFu) * zi;
            v.w = bf2f(t.y >> 16) * zi;
            ((float4*)(pbase + (size_t)o * NCAPS))[c] = v;
        }
    }
}

extern "C" void kernel_launch(void* const* d_in, const int* in_sizes, int n_in,
                              void* d_out, int out_size, void* d_ws, size_t ws_size,
                              hipStream_t stream) {
    const float* x = (const float*)d_in[0];
    const float* w = (const float*)d_in[1];
    float* out = (float*)d_out;
    const int Bv = in_sizes[0] / (NCAPS * ILEN);        // 64
    const int nblocks = Bv * (OCAPS / OG);              // 256
    const int probs_base = Bv * OCAPS * OLEN;           // 65536
    caps_kernel<<<dim3(nblocks), dim3(T), 0, stream>>>(x, w, out, probs_base);
}